// Round 19
// baseline (190.797 us; speedup 1.0000x reference)
//
#include <hip/hip_runtime.h>
#include <hip/hip_bf16.h>
#include <math.h>

#define N_ 8192
#define M_ 4096
#define R_ 12288          // N_ + M_
#define D_ 512
#define C_ 100
#define CP_ 112
#define NSPLIT_ 16
#define MTILES_ ((M_ / NSPLIT_) / 128)   // 2

typedef _Float16 f16;
typedef f16  f16x8 __attribute__((ext_vector_type(8)));
typedef f16  f16x4 __attribute__((ext_vector_type(4)));
typedef float f32x4 __attribute__((ext_vector_type(4)));

__device__ __forceinline__ float mishf(float v) {
    float sp = fmaxf(v, 0.f) + log1pf(expf(-fabsf(v)));
    return v * tanhf(sp);
}

// ---------------- prep: W1/W2 transpose + WpT + zero n2 (one small launch) ----------------
__global__ void prep_all(const float* __restrict__ W1, const float* __restrict__ W2,
                         const float* __restrict__ Wp,
                         f16* __restrict__ w1t, f16* __restrict__ w2t,
                         f16* __restrict__ wpT, float* __restrict__ n2) {
    __shared__ char pshm[57856];
    const int bid = blockIdx.x, t = threadIdx.x;
    if (bid < 128) {
        // W1/W2 transpose via 64x64 LDS tile
        float (*ls)[68] = (float (*)[68])pshm;
        const float* W = (bid < 64) ? W1 : W2;
        f16* WT = (bid < 64) ? w1t : w2t;
        int tile = bid & 63;
        int k0 = (tile >> 3) * 64, c0 = (tile & 7) * 64;
        int r = t >> 4, c4 = (t & 15) * 4;
        #pragma unroll
        for (int l = 0; l < 4; ++l) {
            int row = r + 16 * l;
            float4 v = *reinterpret_cast<const float4*>(&W[(size_t)(k0 + row) * D_ + c0 + c4]);
            ls[row][c4 + 0] = v.x; ls[row][c4 + 1] = v.y;
            ls[row][c4 + 2] = v.z; ls[row][c4 + 3] = v.w;
        }
        __syncthreads();
        #pragma unroll
        for (int l = 0; l < 4; ++l) {
            int c = r + 16 * l;
            f16x4 o;
            #pragma unroll
            for (int j = 0; j < 4; ++j) o[j] = (f16)ls[c4 + j][c];
            *reinterpret_cast<f16x4*>(&WT[(size_t)(c0 + c) * D_ + k0 + c4]) = o;
        }
    } else if (bid < 160) {
        // WpT via 128x112 LDS tile: wpT[c][m] = f16(Wp[m][c]), c padded to 112
        float (*lp)[113] = (float (*)[113])pshm;
        int b = bid - 128;           // 0..31
        int m0 = b * 128;
        for (int id = t; id < 128 * C_; id += 256) {
            int mm = id / C_, c = id - mm * C_;
            lp[mm][c] = Wp[(size_t)(m0 + mm) * C_ + c];
        }
        for (int id = t; id < 128 * (CP_ - C_); id += 256) {
            int mm = id / (CP_ - C_), c = C_ + id % (CP_ - C_);
            lp[mm][c] = 0.f;
        }
        __syncthreads();
        for (int id = t; id < CP_ * 128; id += 256) {
            int c = id >> 7, mm = id & 127;
            wpT[(size_t)c * M_ + m0 + mm] = (f16)lp[mm][c];
        }
    } else {
        // zero n2[R_] (atomic accumulation target for enc2 norms)
        int b = bid - 160;           // 0..15
        int base = b * (R_ / 16) + t;
        #pragma unroll
        for (int l = 0; l < (R_ / 16) / 256; ++l)
            n2[base + l * 256] = 0.f;
    }
}

// ---------------- encoder GEMM + mish on MFMA (64x128 tile, reg-staged) ----------------
// F32IN: A is fp32 (x rows via A1, samples via A2), cast during staging.
// NORMS: per-col-block row-norm partial atomically added into n2.
template<bool NORMS, bool F32IN>
__global__ __launch_bounds__(256) void enc_mfma(
        const void* __restrict__ A1, const void* __restrict__ A2,
        const f16* __restrict__ WT,
        const float* __restrict__ b, f16* __restrict__ out,
        float* __restrict__ n2) {
    __shared__ char smem[24576];
    char* xs = smem;            // [64][128B] = 8 KB
    char* ws = smem + 8192;     // [128][128B] = 16 KB
    char* os = smem;            // [64][256B] = 16 KB output staging (alias)

    const int t = threadIdx.x;
    const int lane = t & 63;
    const int w  = t >> 6;
    const int wr = w >> 1, wc = w & 1;
    const int lr = lane & 15, lk = lane >> 4;
    const int c0 = blockIdx.x * 128;
    const int n0 = blockIdx.y * 64;

    const int srow = t >> 3;              // 0..31
    const int sj   = t & 7;
    const int csA  = sj ^ (srow & 7);     // pre-swizzled source chunk
    // A base: whole 64-row block lies in x or in samples
    const float* Af = nullptr;
    const f16*   Ah = nullptr;
    size_t gA0;
    if constexpr (F32IN) {
        int roff = (n0 < N_) ? n0 : (n0 - N_);
        Af = (const float*)((n0 < N_) ? A1 : A2);
        gA0 = (size_t)(roff + srow) * D_ + csA * 8;
    } else {
        Ah = (const f16*)A1;
        gA0 = (size_t)(n0 + srow) * D_ + csA * 8;
    }
    const size_t gW0 = (size_t)(c0 + srow) * D_ + csA * 8;
    char* lA = xs + t * 16;
    char* lW = ws + t * 16;

    f16x8 ra[2], rw[4];
    f32x4 acc[2][4];
    #pragma unroll
    for (int i = 0; i < 2; ++i)
        #pragma unroll
        for (int j = 0; j < 4; ++j) acc[i][j] = (f32x4){0.f, 0.f, 0.f, 0.f};

    auto loadA = [&](int p, int kn) -> f16x8 {
        if constexpr (F32IN) {
            float4 u0 = *(const float4*)(Af + gA0 + (size_t)p * 32 * D_ + kn);
            float4 u1 = *(const float4*)(Af + gA0 + (size_t)p * 32 * D_ + kn + 4);
            f16x8 o;
            o[0] = (f16)u0.x; o[1] = (f16)u0.y; o[2] = (f16)u0.z; o[3] = (f16)u0.w;
            o[4] = (f16)u1.x; o[5] = (f16)u1.y; o[6] = (f16)u1.z; o[7] = (f16)u1.w;
            return o;
        } else {
            return *(const f16x8*)(Ah + gA0 + (size_t)p * 32 * D_ + kn);
        }
    };

    // prologue: chunk 0
    #pragma unroll
    for (int p = 0; p < 2; ++p) ra[p] = loadA(p, 0);
    #pragma unroll
    for (int p = 0; p < 4; ++p) rw[p] = *(const f16x8*)(WT + gW0 + (size_t)p * 32 * D_);

    for (int kc = 0; kc < 8; ++kc) {
        __syncthreads();
        #pragma unroll
        for (int p = 0; p < 2; ++p) *(f16x8*)(lA + p * 4096) = ra[p];
        #pragma unroll
        for (int p = 0; p < 4; ++p) *(f16x8*)(lW + p * 4096) = rw[p];
        if (kc < 7) {
            int kn = (kc + 1) * 64;
            #pragma unroll
            for (int p = 0; p < 2; ++p) ra[p] = loadA(p, kn);
            #pragma unroll
            for (int p = 0; p < 4; ++p) rw[p] = *(const f16x8*)(WT + gW0 + (size_t)p * 32 * D_ + kn);
        }
        __syncthreads();
        #pragma unroll
        for (int ks = 0; ks < 2; ++ks) {
            const int csw = (ks * 4 + lk) ^ (lr & 7);
            f16x8 af[2], bf[4];
            #pragma unroll
            for (int i = 0; i < 2; ++i)
                af[i] = *(const f16x8*)(xs + (wr * 32 + i * 16 + lr) * 128 + csw * 16);
            #pragma unroll
            for (int j = 0; j < 4; ++j)
                bf[j] = *(const f16x8*)(ws + (wc * 64 + j * 16 + lr) * 128 + csw * 16);
            #pragma unroll
            for (int i = 0; i < 2; ++i)
                #pragma unroll
                for (int j = 0; j < 4; ++j)
                    acc[i][j] = __builtin_amdgcn_mfma_f32_16x16x32_f16(af[i], bf[j], acc[i][j], 0, 0, 0);
        }
    }
    __syncthreads();   // xs/ws reads done before os alias
    {
        float bv[4];
        #pragma unroll
        for (int j = 0; j < 4; ++j) bv[j] = b[c0 + wc * 64 + j * 16 + lr];
        float rn[2][4] = {};
        #pragma unroll
        for (int i = 0; i < 2; ++i)
            #pragma unroll
            for (int j = 0; j < 4; ++j)
                #pragma unroll
                for (int q = 0; q < 4; ++q) {
                    float v = mishf(acc[i][j][q] + bv[j]);
                    f16 h = (f16)v;
                    int row_l = wr * 32 + i * 16 + lk * 4 + q;
                    int col_l = wc * 64 + j * 16 + lr;
                    *(f16*)(os + row_l * 256 + (((col_l >> 3) ^ (row_l & 7)) * 16) + (col_l & 7) * 2) = h;
                    if (NORMS) { float fv = (float)h; rn[i][q] = fmaf(fv, fv, rn[i][q]); }
                }
        if (NORMS) {
            #pragma unroll
            for (int i = 0; i < 2; ++i)
                #pragma unroll
                for (int q = 0; q < 4; ++q) {
                    float s = rn[i][q];
                    s += __shfl_xor(s, 1, 64); s += __shfl_xor(s, 2, 64);
                    s += __shfl_xor(s, 4, 64); s += __shfl_xor(s, 8, 64);
                    if (lr == 0)
                        atomicAdd(&n2[n0 + wr * 32 + i * 16 + lk * 4 + q], s);
                }
        }
    }
    __syncthreads();
    #pragma unroll
    for (int l2 = 0; l2 < 4; ++l2) {
        int id = t + l2 * 256;
        int row = id >> 4, cc = id & 15;
        f16x8 v = *(const f16x8*)(os + row * 256 + ((cc ^ (row & 7)) * 16));
        *(f16x8*)(out + (size_t)(n0 + row) * D_ + c0 + cc * 8) = v;
    }
}

// ---------------- fused distance + projection (MFMA) ----------------
// R18's 37.4 KB kernel + NSPLIT 16: grid 1024 blocks -> 4 blocks/CU (was grid-capped
// at 2). z-phase in two 64-anchor halves; dsH/wpH alias xs/ss.
#define LDA3 72    // f16 stride for ALL tiles (xs/ss/dsH/wpH)
__global__ __launch_bounds__(256, 2) void fused_mfma(
        const f16* __restrict__ xe, const f16* __restrict__ se,
        const float* __restrict__ xn2, const float* __restrict__ sn2,
        const f16* __restrict__ WpT, f16* __restrict__ zpart) {
    __shared__ char smem[37376];
    f16*   xs  = (f16*)smem;               // [128][72] S-phase
    f16*   ss  = (f16*)(smem + 18432);     // [128][72] S-phase
    f16*   dsH = (f16*)smem;               // [128][72] z-half phase (aliases xs)
    f16*   wpH = (f16*)(smem + 18432);     // [112][72] z-half phase (aliases ss)
    float* xn  = (float*)(smem + 36864);   // [128]

    const int t    = threadIdx.x;
    const int lane = t & 63;
    const int w    = t >> 6;
    const int wr   = w >> 1, wc = w & 1;
    const int lr   = lane & 15, lk = lane >> 4;

    const int n0    = blockIdx.x * 128;
    const int mbase = blockIdx.y * (M_ / NSPLIT_);

    if (t < 128) xn[t] = xn2[n0 + t];

    f32x4 zacc[2][7];
    #pragma unroll
    for (int i = 0; i < 2; ++i)
        #pragma unroll
        for (int j = 0; j < 7; ++j)
            zacc[i][j] = (f32x4){0.f, 0.f, 0.f, 0.f};

    for (int mt = 0; mt < MTILES_; ++mt) {
        const int m0 = mbase + mt * 128;
        f32x4 sacc[4][4];
        #pragma unroll
        for (int i = 0; i < 4; ++i)
            #pragma unroll
            for (int j = 0; j < 4; ++j)
                sacc[i][j] = (f32x4){0.f, 0.f, 0.f, 0.f};

        for (int kc = 0; kc < 8; ++kc) {
            __syncthreads();   // prev readers of xs/ss (S-MFMA or z-half reads) done
            {
                int r = t >> 3, ko = (t & 7) * 8;
                int kg = kc * 64 + ko;
                #pragma unroll
                for (int l = 0; l < 4; ++l) {
                    int row = r + 32 * l;
                    *reinterpret_cast<f16x8*>(&xs[row * LDA3 + ko]) =
                        *reinterpret_cast<const f16x8*>(&xe[(size_t)(n0 + row) * D_ + kg]);
                    *reinterpret_cast<f16x8*>(&ss[row * LDA3 + ko]) =
                        *reinterpret_cast<const f16x8*>(&se[(size_t)(m0 + row) * D_ + kg]);
                }
            }
            __syncthreads();
            #pragma unroll
            for (int ks = 0; ks < 2; ++ks) {
                f16x8 af[4], bf[4];
                #pragma unroll
                for (int i = 0; i < 4; ++i) {
                    af[i] = *reinterpret_cast<const f16x8*>(&xs[(wr * 64 + i * 16 + lr) * LDA3 + ks * 32 + lk * 8]);
                    bf[i] = *reinterpret_cast<const f16x8*>(&ss[(wc * 64 + i * 16 + lr) * LDA3 + ks * 32 + lk * 8]);
                }
                #pragma unroll
                for (int i = 0; i < 4; ++i)
                    #pragma unroll
                    for (int j = 0; j < 4; ++j)
                        sacc[i][j] = __builtin_amdgcn_mfma_f32_16x16x32_f16(af[i], bf[j], sacc[i][j], 0, 0, 0);
            }
        }
        // z-phase in two 64-anchor halves; anchor half h owned by wc==h waves
        #pragma unroll
        for (int half = 0; half < 2; ++half) {
            __syncthreads();   // prev reads of xs/ss aliases (S-loop / z-half 0) done
            if (wc == half) {
                float snr[4];
                #pragma unroll
                for (int j = 0; j < 4; ++j) snr[j] = sn2[m0 + half * 64 + j * 16 + lr];
                #pragma unroll
                for (int i = 0; i < 4; ++i) {
                    #pragma unroll
                    for (int j = 0; j < 4; ++j) {
                        #pragma unroll
                        for (int q = 0; q < 4; ++q) {
                            int row_l = wr * 64 + i * 16 + lk * 4 + q;
                            int col_h = j * 16 + lr;
                            float d2 = xn[row_l] + snr[j] - 2.f * sacc[i][j][q];
                            dsH[row_l * LDA3 + col_h] = (f16)sqrtf(fmaxf(d2, 0.f));
                        }
                    }
                }
            }
            // stage wpH [112][64] from WpT[c][m0 + half*64 ..]
            #pragma unroll
            for (int l = 0; l < 4; ++l) {
                int id = t + l * 256;
                if (id < 896) {
                    int c = id >> 3, mo = (id & 7) * 8;
                    *reinterpret_cast<f16x8*>(&wpH[c * LDA3 + mo]) =
                        *reinterpret_cast<const f16x8*>(&WpT[(size_t)c * M_ + m0 + half * 64 + mo]);
                }
            }
            __syncthreads();   // dsH + wpH visible
            #pragma unroll
            for (int ks = 0; ks < 2; ++ks) {
                f16x8 aF0 = *reinterpret_cast<const f16x8*>(&dsH[(w * 32 + 0  + lr) * LDA3 + ks * 32 + lk * 8]);
                f16x8 aF1 = *reinterpret_cast<const f16x8*>(&dsH[(w * 32 + 16 + lr) * LDA3 + ks * 32 + lk * 8]);
                #pragma unroll
                for (int cb = 0; cb < 7; ++cb) {
                    f16x8 bF = *reinterpret_cast<const f16x8*>(&wpH[(cb * 16 + lr) * LDA3 + ks * 32 + lk * 8]);
                    zacc[0][cb] = __builtin_amdgcn_mfma_f32_16x16x32_f16(aF0, bF, zacc[0][cb], 0, 0, 0);
                    zacc[1][cb] = __builtin_amdgcn_mfma_f32_16x16x32_f16(aF1, bF, zacc[1][cb], 0, 0, 0);
                }
            }
        }
    }
    #pragma unroll
    for (int ar = 0; ar < 2; ++ar) {
        #pragma unroll
        for (int cb = 0; cb < 7; ++cb) {
            #pragma unroll
            for (int q = 0; q < 4; ++q) {
                int row = n0 + w * 32 + ar * 16 + lk * 4 + q;
                int col = cb * 16 + lr;
                zpart[((size_t)blockIdx.y * N_ + row) * CP_ + col] = (f16)zacc[ar][cb][q];
            }
        }
    }
}

// reduce splits + bias + tanh + log_softmax; 4 rows per 256-thread block
__global__ void z_epilogue(const f16* __restrict__ zpart, const float* __restrict__ bp,
                           float* __restrict__ out) {
    const int w = threadIdx.x >> 6, lane = threadIdx.x & 63;
    const int row = blockIdx.x * 4 + w;
    float z0 = 0.f, z1 = 0.f;
    #pragma unroll
    for (int s = 0; s < NSPLIT_; ++s) {
        const f16* zp = &zpart[((size_t)s * N_ + row) * CP_];
        z0 += (float)zp[lane];
        if (lane + 64 < CP_) z1 += (float)zp[lane + 64];
    }
    float t0 = tanhf(z0 + bp[lane]);
    bool  v1 = (lane + 64) < C_;
    float t1 = v1 ? tanhf(z1 + bp[lane + 64]) : -INFINITY;
    float mx = fmaxf(t0, t1);
    #pragma unroll
    for (int m = 1; m < 64; m <<= 1) mx = fmaxf(mx, __shfl_xor(mx, m, 64));
    float se_ = expf(t0 - mx) + (v1 ? expf(t1 - mx) : 0.f);
    #pragma unroll
    for (int m = 1; m < 64; m <<= 1) se_ += __shfl_xor(se_, m, 64);
    float lse = mx + logf(se_);
    out[(size_t)row * C_ + lane] = t0 - lse;
    if (v1) out[(size_t)row * C_ + lane + 64] = t1 - lse;
}

extern "C" void kernel_launch(void* const* d_in, const int* in_sizes, int n_in,
                              void* d_out, int out_size, void* d_ws, size_t ws_size,
                              hipStream_t stream) {
    const float* x       = (const float*)d_in[0];
    const float* samples = (const float*)d_in[1];
    const float* W1      = (const float*)d_in[2];
    const float* b1      = (const float*)d_in[3];
    const float* W2      = (const float*)d_in[4];
    const float* b2      = (const float*)d_in[5];
    const float* Wp      = (const float*)d_in[6];
    const float* bp      = (const float*)d_in[7];
    float* out = (float*)d_out;

    char* p = (char*)d_ws;
    f16* zpart = (f16*)p;                           // 16*8192*112*2 = 29,360,128 B
    // aliases inside the region (h dead before fused_mfma writes zpart):
    f16* h   = (f16*)(p + 12582912);                // 12,582,912 B  (layer-1 out)
    f16* w1t = (f16*)(p + 25165824);                //    524,288 B
    f16* w2t = (f16*)(p + 25690112);                //    524,288 B
    p += 29360128;                                  // zpart region (exact fit at 16 splits)
    f16*  ef  = (f16*)p;   p += (size_t)R_ * D_ * 2;    // 12,582,912
    float* n2  = (float*)p; p += (size_t)R_ * 4;        //     49,152
    f16*  wpT = (f16*)p;   p += (size_t)CP_ * M_ * 2;   //    917,504

    dim3 blk(256);
    prep_all<<<176, blk, 0, stream>>>(W1, W2, Wp, w1t, w2t, wpT, n2);
    // layer 1: fp32 x/samples read directly, cast during staging
    enc_mfma<false, true><<<dim3(4, R_ / 64), blk, 0, stream>>>(x, samples, w1t, b1, h, nullptr);
    // layer 2: f16 h -> ef, norms atomically accumulated into n2
    enc_mfma<true, false><<<dim3(4, R_ / 64), blk, 0, stream>>>(h, nullptr, w2t, b2, ef, n2);
    fused_mfma<<<dim3(N_ / 128, NSPLIT_), blk, 0, stream>>>(ef, ef + (size_t)N_ * D_,
                                                           n2, n2 + N_, wpT, zpart);
    z_epilogue<<<N_ / 4, blk, 0, stream>>>(zpart, bp, out);
}

// Round 20
// 169.093 us; speedup vs baseline: 1.1284x; 1.1284x over previous
//
#include <hip/hip_runtime.h>
#include <hip/hip_bf16.h>
#include <math.h>

#define N_ 8192
#define M_ 4096
#define R_ 12288          // N_ + M_
#define D_ 512
#define C_ 100
#define CP_ 112
#define NSPLIT_ 8
#define MTILES_ ((M_ / NSPLIT_) / 128)   // 4

typedef _Float16 f16;
typedef f16  f16x8 __attribute__((ext_vector_type(8)));
typedef f16  f16x4 __attribute__((ext_vector_type(4)));
typedef float f32x4 __attribute__((ext_vector_type(4)));

__device__ __forceinline__ float mishf(float v) {
    float sp = fmaxf(v, 0.f) + log1pf(expf(-fabsf(v)));
    return v * tanhf(sp);
}

// ---------------- prep: W1/W2 transpose + WpT + zero n2 (one small launch) ----------------
__global__ void prep_all(const float* __restrict__ W1, const float* __restrict__ W2,
                         const float* __restrict__ Wp,
                         f16* __restrict__ w1t, f16* __restrict__ w2t,
                         f16* __restrict__ wpT, float* __restrict__ n2) {
    __shared__ char pshm[57856];
    const int bid = blockIdx.x, t = threadIdx.x;
    if (bid < 128) {
        // W1/W2 transpose via 64x64 LDS tile
        float (*ls)[68] = (float (*)[68])pshm;
        const float* W = (bid < 64) ? W1 : W2;
        f16* WT = (bid < 64) ? w1t : w2t;
        int tile = bid & 63;
        int k0 = (tile >> 3) * 64, c0 = (tile & 7) * 64;
        int r = t >> 4, c4 = (t & 15) * 4;
        #pragma unroll
        for (int l = 0; l < 4; ++l) {
            int row = r + 16 * l;
            float4 v = *reinterpret_cast<const float4*>(&W[(size_t)(k0 + row) * D_ + c0 + c4]);
            ls[row][c4 + 0] = v.x; ls[row][c4 + 1] = v.y;
            ls[row][c4 + 2] = v.z; ls[row][c4 + 3] = v.w;
        }
        __syncthreads();
        #pragma unroll
        for (int l = 0; l < 4; ++l) {
            int c = r + 16 * l;
            f16x4 o;
            #pragma unroll
            for (int j = 0; j < 4; ++j) o[j] = (f16)ls[c4 + j][c];
            *reinterpret_cast<f16x4*>(&WT[(size_t)(c0 + c) * D_ + k0 + c4]) = o;
        }
    } else if (bid < 160) {
        // WpT via 128x112 LDS tile: wpT[c][m] = f16(Wp[m][c]), c padded to 112
        float (*lp)[113] = (float (*)[113])pshm;
        int b = bid - 128;           // 0..31
        int m0 = b * 128;
        for (int id = t; id < 128 * C_; id += 256) {
            int mm = id / C_, c = id - mm * C_;
            lp[mm][c] = Wp[(size_t)(m0 + mm) * C_ + c];
        }
        for (int id = t; id < 128 * (CP_ - C_); id += 256) {
            int mm = id / (CP_ - C_), c = C_ + id % (CP_ - C_);
            lp[mm][c] = 0.f;
        }
        __syncthreads();
        for (int id = t; id < CP_ * 128; id += 256) {
            int c = id >> 7, mm = id & 127;
            wpT[(size_t)c * M_ + m0 + mm] = (f16)lp[mm][c];
        }
    } else {
        // zero n2[R_] (atomic accumulation target for enc2 norms)
        int b = bid - 160;           // 0..15
        int base = b * (R_ / 16) + t;
        #pragma unroll
        for (int l = 0; l < (R_ / 16) / 256; ++l)
            n2[base + l * 256] = 0.f;
    }
}

// ---------------- encoder GEMM + mish on MFMA (64x128 tile, reg-staged) ----------------
// F32IN: A is fp32 (x rows via A1, samples via A2), cast during staging.
// NORMS: per-col-block row-norm partial atomically added into n2.
template<bool NORMS, bool F32IN>
__global__ __launch_bounds__(256) void enc_mfma(
        const void* __restrict__ A1, const void* __restrict__ A2,
        const f16* __restrict__ WT,
        const float* __restrict__ b, f16* __restrict__ out,
        float* __restrict__ n2) {
    __shared__ char smem[24576];
    char* xs = smem;            // [64][128B] = 8 KB
    char* ws = smem + 8192;     // [128][128B] = 16 KB
    char* os = smem;            // [64][256B] = 16 KB output staging (alias)

    const int t = threadIdx.x;
    const int lane = t & 63;
    const int w  = t >> 6;
    const int wr = w >> 1, wc = w & 1;
    const int lr = lane & 15, lk = lane >> 4;
    const int c0 = blockIdx.x * 128;
    const int n0 = blockIdx.y * 64;

    const int srow = t >> 3;              // 0..31
    const int sj   = t & 7;
    const int csA  = sj ^ (srow & 7);     // pre-swizzled source chunk
    // A base: whole 64-row block lies in x or in samples
    const float* Af = nullptr;
    const f16*   Ah = nullptr;
    size_t gA0;
    if constexpr (F32IN) {
        int roff = (n0 < N_) ? n0 : (n0 - N_);
        Af = (const float*)((n0 < N_) ? A1 : A2);
        gA0 = (size_t)(roff + srow) * D_ + csA * 8;
    } else {
        Ah = (const f16*)A1;
        gA0 = (size_t)(n0 + srow) * D_ + csA * 8;
    }
    const size_t gW0 = (size_t)(c0 + srow) * D_ + csA * 8;
    char* lA = xs + t * 16;
    char* lW = ws + t * 16;

    f16x8 ra[2], rw[4];
    f32x4 acc[2][4];
    #pragma unroll
    for (int i = 0; i < 2; ++i)
        #pragma unroll
        for (int j = 0; j < 4; ++j) acc[i][j] = (f32x4){0.f, 0.f, 0.f, 0.f};

    auto loadA = [&](int p, int kn) -> f16x8 {
        if constexpr (F32IN) {
            float4 u0 = *(const float4*)(Af + gA0 + (size_t)p * 32 * D_ + kn);
            float4 u1 = *(const float4*)(Af + gA0 + (size_t)p * 32 * D_ + kn + 4);
            f16x8 o;
            o[0] = (f16)u0.x; o[1] = (f16)u0.y; o[2] = (f16)u0.z; o[3] = (f16)u0.w;
            o[4] = (f16)u1.x; o[5] = (f16)u1.y; o[6] = (f16)u1.z; o[7] = (f16)u1.w;
            return o;
        } else {
            return *(const f16x8*)(Ah + gA0 + (size_t)p * 32 * D_ + kn);
        }
    };

    // prologue: chunk 0
    #pragma unroll
    for (int p = 0; p < 2; ++p) ra[p] = loadA(p, 0);
    #pragma unroll
    for (int p = 0; p < 4; ++p) rw[p] = *(const f16x8*)(WT + gW0 + (size_t)p * 32 * D_);

    for (int kc = 0; kc < 8; ++kc) {
        __syncthreads();
        #pragma unroll
        for (int p = 0; p < 2; ++p) *(f16x8*)(lA + p * 4096) = ra[p];
        #pragma unroll
        for (int p = 0; p < 4; ++p) *(f16x8*)(lW + p * 4096) = rw[p];
        if (kc < 7) {
            int kn = (kc + 1) * 64;
            #pragma unroll
            for (int p = 0; p < 2; ++p) ra[p] = loadA(p, kn);
            #pragma unroll
            for (int p = 0; p < 4; ++p) rw[p] = *(const f16x8*)(WT + gW0 + (size_t)p * 32 * D_ + kn);
        }
        __syncthreads();
        #pragma unroll
        for (int ks = 0; ks < 2; ++ks) {
            const int csw = (ks * 4 + lk) ^ (lr & 7);
            f16x8 af[2], bf[4];
            #pragma unroll
            for (int i = 0; i < 2; ++i)
                af[i] = *(const f16x8*)(xs + (wr * 32 + i * 16 + lr) * 128 + csw * 16);
            #pragma unroll
            for (int j = 0; j < 4; ++j)
                bf[j] = *(const f16x8*)(ws + (wc * 64 + j * 16 + lr) * 128 + csw * 16);
            #pragma unroll
            for (int i = 0; i < 2; ++i)
                #pragma unroll
                for (int j = 0; j < 4; ++j)
                    acc[i][j] = __builtin_amdgcn_mfma_f32_16x16x32_f16(af[i], bf[j], acc[i][j], 0, 0, 0);
        }
    }
    __syncthreads();   // xs/ws reads done before os alias
    {
        float bv[4];
        #pragma unroll
        for (int j = 0; j < 4; ++j) bv[j] = b[c0 + wc * 64 + j * 16 + lr];
        float rn[2][4] = {};
        #pragma unroll
        for (int i = 0; i < 2; ++i)
            #pragma unroll
            for (int j = 0; j < 4; ++j)
                #pragma unroll
                for (int q = 0; q < 4; ++q) {
                    float v = mishf(acc[i][j][q] + bv[j]);
                    f16 h = (f16)v;
                    int row_l = wr * 32 + i * 16 + lk * 4 + q;
                    int col_l = wc * 64 + j * 16 + lr;
                    *(f16*)(os + row_l * 256 + (((col_l >> 3) ^ (row_l & 7)) * 16) + (col_l & 7) * 2) = h;
                    if (NORMS) { float fv = (float)h; rn[i][q] = fmaf(fv, fv, rn[i][q]); }
                }
        if (NORMS) {
            #pragma unroll
            for (int i = 0; i < 2; ++i)
                #pragma unroll
                for (int q = 0; q < 4; ++q) {
                    float s = rn[i][q];
                    s += __shfl_xor(s, 1, 64); s += __shfl_xor(s, 2, 64);
                    s += __shfl_xor(s, 4, 64); s += __shfl_xor(s, 8, 64);
                    if (lr == 0)
                        atomicAdd(&n2[n0 + wr * 32 + i * 16 + lk * 4 + q], s);
                }
        }
    }
    __syncthreads();
    #pragma unroll
    for (int l2 = 0; l2 < 4; ++l2) {
        int id = t + l2 * 256;
        int row = id >> 4, cc = id & 15;
        f16x8 v = *(const f16x8*)(os + row * 256 + ((cc ^ (row & 7)) * 16));
        *(f16x8*)(out + (size_t)(n0 + row) * D_ + c0 + cc * 8) = v;
    }
}

// ---------------- fused distance + projection (MFMA) — R13 kernel (best verified) ----------------
#define LDA3 72    // f16 stride for xe/se tiles
#define LDD3 136   // f16 stride for dist / wp tiles
__global__ __launch_bounds__(256, 2) void fused_mfma(
        const f16* __restrict__ xe, const f16* __restrict__ se,
        const float* __restrict__ xn2, const float* __restrict__ sn2,
        const f16* __restrict__ WpT, f16* __restrict__ zpart) {
    __shared__ char smem[72192];
    f16*   xs = (f16*)smem;               // [128][72]
    f16*   ss = (f16*)(smem + 18432);     // [128][72]
    f16*   wp = (f16*)smem;               // [112][136]  (aliases xs/ss)
    f16*   ds = (f16*)(smem + 36864);     // [128][136]
    float* xn = (float*)(smem + 71680);   // [128]

    const int t    = threadIdx.x;
    const int lane = t & 63;
    const int w    = t >> 6;
    const int wr   = w >> 1, wc = w & 1;
    const int lr   = lane & 15, lk = lane >> 4;

    const int n0    = blockIdx.x * 128;
    const int mbase = blockIdx.y * (M_ / NSPLIT_);

    if (t < 128) xn[t] = xn2[n0 + t];

    f32x4 zacc[2][7];
    #pragma unroll
    for (int i = 0; i < 2; ++i)
        #pragma unroll
        for (int j = 0; j < 7; ++j)
            zacc[i][j] = (f32x4){0.f, 0.f, 0.f, 0.f};

    for (int mt = 0; mt < MTILES_; ++mt) {
        const int m0 = mbase + mt * 128;
        f32x4 sacc[4][4];
        #pragma unroll
        for (int i = 0; i < 4; ++i)
            #pragma unroll
            for (int j = 0; j < 4; ++j)
                sacc[i][j] = (f32x4){0.f, 0.f, 0.f, 0.f};

        for (int kc = 0; kc < 8; ++kc) {
            __syncthreads();
            {
                int r = t >> 3, ko = (t & 7) * 8;
                int kg = kc * 64 + ko;
                #pragma unroll
                for (int l = 0; l < 4; ++l) {
                    int row = r + 32 * l;
                    *reinterpret_cast<f16x8*>(&xs[row * LDA3 + ko]) =
                        *reinterpret_cast<const f16x8*>(&xe[(size_t)(n0 + row) * D_ + kg]);
                    *reinterpret_cast<f16x8*>(&ss[row * LDA3 + ko]) =
                        *reinterpret_cast<const f16x8*>(&se[(size_t)(m0 + row) * D_ + kg]);
                }
            }
            __syncthreads();
            #pragma unroll
            for (int ks = 0; ks < 2; ++ks) {
                f16x8 af[4], bf[4];
                #pragma unroll
                for (int i = 0; i < 4; ++i) {
                    af[i] = *reinterpret_cast<const f16x8*>(&xs[(wr * 64 + i * 16 + lr) * LDA3 + ks * 32 + lk * 8]);
                    bf[i] = *reinterpret_cast<const f16x8*>(&ss[(wc * 64 + i * 16 + lr) * LDA3 + ks * 32 + lk * 8]);
                }
                #pragma unroll
                for (int i = 0; i < 4; ++i)
                    #pragma unroll
                    for (int j = 0; j < 4; ++j)
                        sacc[i][j] = __builtin_amdgcn_mfma_f32_16x16x32_f16(af[i], bf[j], sacc[i][j], 0, 0, 0);
            }
        }
        {
            float snr[4];
            #pragma unroll
            for (int j = 0; j < 4; ++j) snr[j] = sn2[m0 + wc * 64 + j * 16 + lr];
            #pragma unroll
            for (int i = 0; i < 4; ++i) {
                #pragma unroll
                for (int j = 0; j < 4; ++j) {
                    #pragma unroll
                    for (int q = 0; q < 4; ++q) {
                        int row_l = wr * 64 + i * 16 + lk * 4 + q;
                        int col_l = wc * 64 + j * 16 + lr;
                        float d2 = xn[row_l] + snr[j] - 2.f * sacc[i][j][q];
                        ds[row_l * LDD3 + col_l] = (f16)sqrtf(fmaxf(d2, 0.f));
                    }
                }
            }
        }
        __syncthreads();           // S reads done -> wp may overwrite xs/ss; ds visible
        #pragma unroll
        for (int l = 0; l < 7; ++l) {
            int id = t + l * 256;
            int c = id >> 4, mo = (id & 15) * 8;
            *reinterpret_cast<f16x8*>(&wp[c * LDD3 + mo]) =
                *reinterpret_cast<const f16x8*>(&WpT[(size_t)c * M_ + m0 + mo]);
        }
        __syncthreads();
        #pragma unroll
        for (int ks = 0; ks < 4; ++ks) {
            f16x8 aF0 = *reinterpret_cast<const f16x8*>(&ds[(w * 32 + 0  + lr) * LDD3 + ks * 32 + lk * 8]);
            f16x8 aF1 = *reinterpret_cast<const f16x8*>(&ds[(w * 32 + 16 + lr) * LDD3 + ks * 32 + lk * 8]);
            #pragma unroll
            for (int cb = 0; cb < 7; ++cb) {
                f16x8 bF = *reinterpret_cast<const f16x8*>(&wp[(cb * 16 + lr) * LDD3 + ks * 32 + lk * 8]);
                zacc[0][cb] = __builtin_amdgcn_mfma_f32_16x16x32_f16(aF0, bF, zacc[0][cb], 0, 0, 0);
                zacc[1][cb] = __builtin_amdgcn_mfma_f32_16x16x32_f16(aF1, bF, zacc[1][cb], 0, 0, 0);
            }
        }
    }
    #pragma unroll
    for (int ar = 0; ar < 2; ++ar) {
        #pragma unroll
        for (int cb = 0; cb < 7; ++cb) {
            #pragma unroll
            for (int q = 0; q < 4; ++q) {
                int row = n0 + w * 32 + ar * 16 + lk * 4 + q;
                int col = cb * 16 + lr;
                zpart[((size_t)blockIdx.y * N_ + row) * CP_ + col] = (f16)zacc[ar][cb][q];
            }
        }
    }
}

// reduce splits + bias + tanh + log_softmax; 4 rows per 256-thread block
__global__ void z_epilogue(const f16* __restrict__ zpart, const float* __restrict__ bp,
                           float* __restrict__ out) {
    const int w = threadIdx.x >> 6, lane = threadIdx.x & 63;
    const int row = blockIdx.x * 4 + w;
    float z0 = 0.f, z1 = 0.f;
    #pragma unroll
    for (int s = 0; s < NSPLIT_; ++s) {
        const f16* zp = &zpart[((size_t)s * N_ + row) * CP_];
        z0 += (float)zp[lane];
        if (lane + 64 < CP_) z1 += (float)zp[lane + 64];
    }
    float t0 = tanhf(z0 + bp[lane]);
    bool  v1 = (lane + 64) < C_;
    float t1 = v1 ? tanhf(z1 + bp[lane + 64]) : -INFINITY;
    float mx = fmaxf(t0, t1);
    #pragma unroll
    for (int m = 1; m < 64; m <<= 1) mx = fmaxf(mx, __shfl_xor(mx, m, 64));
    float se_ = expf(t0 - mx) + (v1 ? expf(t1 - mx) : 0.f);
    #pragma unroll
    for (int m = 1; m < 64; m <<= 1) se_ += __shfl_xor(se_, m, 64);
    float lse = mx + logf(se_);
    out[(size_t)row * C_ + lane] = t0 - lse;
    if (v1) out[(size_t)row * C_ + lane + 64] = t1 - lse;
}

extern "C" void kernel_launch(void* const* d_in, const int* in_sizes, int n_in,
                              void* d_out, int out_size, void* d_ws, size_t ws_size,
                              hipStream_t stream) {
    const float* x       = (const float*)d_in[0];
    const float* samples = (const float*)d_in[1];
    const float* W1      = (const float*)d_in[2];
    const float* b1      = (const float*)d_in[3];
    const float* W2      = (const float*)d_in[4];
    const float* b2      = (const float*)d_in[5];
    const float* Wp      = (const float*)d_in[6];
    const float* bp      = (const float*)d_in[7];
    float* out = (float*)d_out;

    char* p = (char*)d_ws;
    f16* zpart = (f16*)p;                           // 8*8192*112*2 = 14,680,064 B
    // aliases inside the region (h dead before fused_mfma writes zpart):
    f16* h   = (f16*)(p + 12582912);                // 12,582,912 B  (layer-1 out)
    f16* w1t = (f16*)(p + 25165824);                //    524,288 B
    f16* w2t = (f16*)(p + 25690112);                //    524,288 B
    p += 29360128;                                  // keep layout stable
    f16*  ef  = (f16*)p;   p += (size_t)R_ * D_ * 2;    // 12,582,912
    float* n2  = (float*)p; p += (size_t)R_ * 4;        //     49,152
    f16*  wpT = (f16*)p;   p += (size_t)CP_ * M_ * 2;   //    917,504

    dim3 blk(256);
    prep_all<<<176, blk, 0, stream>>>(W1, W2, Wp, w1t, w2t, wpT, n2);
    // layer 1: fp32 x/samples read directly, cast during staging
    enc_mfma<false, true><<<dim3(4, R_ / 64), blk, 0, stream>>>(x, samples, w1t, b1, h, nullptr);
    // layer 2: f16 h -> ef, norms atomically accumulated into n2
    enc_mfma<true, false><<<dim3(4, R_ / 64), blk, 0, stream>>>(h, nullptr, w2t, b2, ef, n2);
    fused_mfma<<<dim3(N_ / 128, NSPLIT_), blk, 0, stream>>>(ef, ef + (size_t)N_ * D_,
                                                           n2, n2 + N_, wpT, zpart);
    z_epilogue<<<N_ / 4, blk, 0, stream>>>(zpart, bp, out);
}